// Round 8
// baseline (2045.662 us; speedup 1.0000x reference)
//
#include <hip/hip_runtime.h>
#include <cmath>

// Problem constants
#define B_   512
#define L_   200
#define V_   50000
#define E_   256
#define H_   128     // per-direction hidden
#define G4H_ 512     // 4*H
#define D_   256     // 2*H
#define T_   6

__device__ __forceinline__ float sigmoidf_(float x) { return 1.0f / (1.0f + __expf(-x)); }
__device__ __forceinline__ float leakyf_(float x)   { return x >= 0.0f ? x : 0.01f * x; }

// DPP quad-perm add (VALU pipe — NOT ds_bpermute/LDS). CTRL: xor1=0xB1, xor2=0x4E.
template<int CTRL>
__device__ __forceinline__ float dpp_add_(float x) {
    const int m = __builtin_amdgcn_mov_dpp(__float_as_int(x), CTRL, 0xF, 0xF, true);
    return x + __int_as_float(m);
}

// ---------------------------------------------------------------------------
// K1: xg GEMM, 128x128 tile, 8x8 micro-tile, BK=8, ping-pong double buffer.
// NEW: __launch_bounds__(256,4) pins VGPR <= 128 (the m69 cliff) -> 4
// waves/SIMD. k-loop live set ~105 regs, so no in-loop spill expected.
// ---------------------------------------------------------------------------
#define XBM 128
#define XBN 128
#define XBK 8
#define XSTR 132

__global__ __launch_bounds__(256, 4) void gemm_xg_chunk(
    const int* __restrict__ sent, const float* __restrict__ emb,
    const float* __restrict__ Wf, const float* __restrict__ Wb,
    const float* __restrict__ bihf, const float* __restrict__ bhhf,
    const float* __restrict__ bihb, const float* __restrict__ bhhb,
    float* __restrict__ xgc, int c0, int tc)
{
    __shared__ float As[2][XBK][XSTR];
    __shared__ float Bs[2][XBK][XSTR];
    __shared__ int   tok[XBM];

    const int bm  = blockIdx.x;       // 0 .. 8*tc-1
    const int bn  = blockIdx.y;       // 0..3 (N=512 per dir)
    const int tid = threadIdx.x;
    const int half = B_ * tc;         // rows per direction
    const int dir  = (bm * XBM) >= half;  // uniform (B*tc % 128 == 0)

    if (tid < XBM) {
        const int vm  = bm * XBM + tid;
        const int rem = vm - dir * half;
        const int b   = rem / tc;
        const int ti  = rem - b * tc;
        const int s   = c0 + ti;
        const int t   = dir ? (L_ - 1 - s) : s;
        tok[tid] = sent[b * L_ + t];
    }
    __syncthreads();

    const int tx = tid & 15;          // n quad: tx*4 and 64+tx*4
    const int ty = tid >> 4;          // m quad: ty*4 and 64+ty*4
    const int n0 = bn * XBN;

    const float* W   = dir ? Wb   : Wf;
    const float* bih = dir ? bihb : bihf;
    const float* bhh = dir ? bhhb : bhhf;

    const int am = tid >> 1;          // staging row 0..127
    const int ak = (tid & 1) * 4;     // staging k 0 or 4

    const float* arow = emb + (size_t)tok[am] * E_ + ak;
    const float* brow = W + (size_t)(n0 + am) * E_ + ak;

    float acc[8][8];
#pragma unroll
    for (int i = 0; i < 8; ++i)
#pragma unroll
        for (int j = 0; j < 8; ++j) acc[i][j] = 0.0f;

    // prologue: stage slice 0
    {
        const float4 a = *(const float4*)(arow);
        const float4 b = *(const float4*)(brow);
        As[0][ak + 0][am] = a.x; As[0][ak + 1][am] = a.y;
        As[0][ak + 2][am] = a.z; As[0][ak + 3][am] = a.w;
        Bs[0][ak + 0][am] = b.x; Bs[0][ak + 1][am] = b.y;
        Bs[0][ak + 2][am] = b.z; Bs[0][ak + 3][am] = b.w;
    }
    __syncthreads();

    const int NIT = E_ / XBK;         // 32
    for (int it = 0; it < NIT; ++it) {
        const int cur = it & 1;
        const int kn  = (it + 1) * XBK;
        float4 na, nb;
        if (kn < E_) {
            na = *(const float4*)(arow + kn);
            nb = *(const float4*)(brow + kn);
        }
#pragma unroll
        for (int k = 0; k < XBK; ++k) {
            float a[8], bb[8];
            *(float4*)a        = *(const float4*)&As[cur][k][ty * 4];
            *(float4*)(a + 4)  = *(const float4*)&As[cur][k][64 + ty * 4];
            *(float4*)(bb)     = *(const float4*)&Bs[cur][k][tx * 4];
            *(float4*)(bb + 4) = *(const float4*)&Bs[cur][k][64 + tx * 4];
#pragma unroll
            for (int i = 0; i < 8; ++i)
#pragma unroll
                for (int j = 0; j < 8; ++j) acc[i][j] += a[i] * bb[j];
        }
        if (kn < E_) {
            const int nxt = cur ^ 1;
            As[nxt][ak + 0][am] = na.x; As[nxt][ak + 1][am] = na.y;
            As[nxt][ak + 2][am] = na.z; As[nxt][ak + 3][am] = na.w;
            Bs[nxt][ak + 0][am] = nb.x; Bs[nxt][ak + 1][am] = nb.y;
            Bs[nxt][ak + 2][am] = nb.z; Bs[nxt][ak + 3][am] = nb.w;
        }
        __syncthreads();
    }

    // epilogue: bias + store.
    const int nb0i = n0 + tx * 4;
    const int nb1i = n0 + 64 + tx * 4;
    float bias[8];
#pragma unroll
    for (int j = 0; j < 4; ++j) {
        bias[j]     = bih[nb0i + j] + bhh[nb0i + j];
        bias[4 + j] = bih[nb1i + j] + bhh[nb1i + j];
    }
#pragma unroll
    for (int i = 0; i < 8; ++i) {
        const int row = bm * XBM + ((i < 4) ? (ty * 4 + i) : (64 + ty * 4 + i - 4));
        float* dst = xgc + (size_t)row * G4H_;
        float4 v0, v1;
        v0.x = acc[i][0] + bias[0]; v0.y = acc[i][1] + bias[1];
        v0.z = acc[i][2] + bias[2]; v0.w = acc[i][3] + bias[3];
        v1.x = acc[i][4] + bias[4]; v1.y = acc[i][5] + bias[5];
        v1.z = acc[i][6] + bias[6]; v1.w = acc[i][7] + bias[7];
        *(float4*)(dst + nb0i) = v0;
        *(float4*)(dst + nb1i) = v1;
    }
}

// ---------------------------------------------------------------------------
// K2 (v4, unchanged): LSTM scan, split-K + DPP quad reduce, one barrier/step.
// ---------------------------------------------------------------------------
__global__ __launch_bounds__(512, 2) void lstm_scan_chunk(
    const float* __restrict__ xgc,
    const float* __restrict__ Whh_f, const float* __restrict__ Whh_b,
    float* __restrict__ state, float* __restrict__ hcat, int c0, int tc)
{
    const int wg  = blockIdx.x;      // 0..255
    const int dir = wg >> 7;
    const int b0  = (wg & 127) * 4;  // 4 samples per wg
    const int tid = threadIdx.x;     // 0..511

    const int q  = tid & 3;          // k-quarter AND this lane's sample
    const int g2 = tid >> 2;         // hidden j / gate-group 0..127

    const float* Whh = dir ? Whh_b : Whh_f;

    float w[4][32];
#pragma unroll
    for (int p = 0; p < 4; ++p) {
        const float* wr = Whh + (size_t)(g2 + 128 * p) * H_ + q * 32;
#pragma unroll
        for (int kk = 0; kk < 32; kk += 4) {
            const float4 v = *(const float4*)(wr + kk);
            w[p][kk] = v.x; w[p][kk + 1] = v.y; w[p][kk + 2] = v.z; w[p][kk + 3] = v.w;
        }
    }

    __shared__ float hbuf[2][4 * 132];   // [parity][quarter q'*132 + kk*4 + s]

    float c, hval;
    if (c0 == 0) {
        hval = 0.0f;
        c    = 0.0f;
    } else {
        hval = state[((size_t)(dir * B_ + b0 + q) * 2 + 0) * H_ + g2];
        c    = state[((size_t)(dir * B_ + b0 + q) * 2 + 1) * H_ + g2];
    }
    hbuf[0][(g2 >> 5) * 132 + (g2 & 31) * 4 + q] = hval;

    const int t0    = dir ? (L_ - 1 - c0) : c0;
    const int hstep = dir ? -D_ : D_;

    const float* xq = xgc + ((size_t)(dir * B_ + b0 + q) * tc) * G4H_ + g2;
    float* hp = hcat + ((size_t)(b0 + q) * L_ + t0) * D_ + dir * H_ + g2;

    __syncthreads();

    for (int t = 0; t < tc; ++t) {
        const int par = t & 1;
        const float* hq = &hbuf[par][q * 132];

        float xg[4];
#pragma unroll
        for (int p = 0; p < 4; ++p) xg[p] = xq[128 * p];
        xq += G4H_;

        float acc[4][4];
#pragma unroll
        for (int p = 0; p < 4; ++p)
#pragma unroll
            for (int s = 0; s < 4; ++s) acc[p][s] = 0.0f;

#pragma unroll
        for (int kk = 0; kk < 32; ++kk) {
            const float4 hv = *(const float4*)(hq + kk * 4);
#pragma unroll
            for (int p = 0; p < 4; ++p) {
                acc[p][0] += w[p][kk] * hv.x;
                acc[p][1] += w[p][kk] * hv.y;
                acc[p][2] += w[p][kk] * hv.z;
                acc[p][3] += w[p][kk] * hv.w;
            }
        }

#pragma unroll
        for (int p = 0; p < 4; ++p)
#pragma unroll
            for (int s = 0; s < 4; ++s) {
                float v = acc[p][s];
                v = dpp_add_<0xB1>(v);
                v = dpp_add_<0x4E>(v);
                acc[p][s] = v;
            }

        float gi = acc[0][0], gf = acc[1][0], gg = acc[2][0], go = acc[3][0];
        if (q == 1) { gi = acc[0][1]; gf = acc[1][1]; gg = acc[2][1]; go = acc[3][1]; }
        if (q == 2) { gi = acc[0][2]; gf = acc[1][2]; gg = acc[2][2]; go = acc[3][2]; }
        if (q == 3) { gi = acc[0][3]; gf = acc[1][3]; gg = acc[2][3]; go = acc[3][3]; }
        gi += xg[0]; gf += xg[1]; gg += xg[2]; go += xg[3];

        c    = sigmoidf_(gf) * c + sigmoidf_(gi) * tanhf(gg);
        hval = sigmoidf_(go) * tanhf(c);

        hbuf[par ^ 1][(g2 >> 5) * 132 + (g2 & 31) * 4 + q] = hval;
        hp[0] = hval;
        hp += hstep;
        __syncthreads();
    }

    state[((size_t)(dir * B_ + b0 + q) * 2 + 0) * H_ + g2] = hval;
    state[((size_t)(dir * B_ + b0 + q) * 2 + 1) * H_ + g2] = c;
}

// ---------------------------------------------------------------------------
// K3a: MLP1, 128x128/8x8 GEMM, now with the 128-VGPR cap.
// h1 = leaky(hcat @ W1^T + b1). Grid (800, 2).
// ---------------------------------------------------------------------------
__global__ __launch_bounds__(256, 4) void mlp1_gemm(
    const float* __restrict__ hcat,
    const float* __restrict__ W1, const float* __restrict__ b1,
    float* __restrict__ h1)
{
    __shared__ float As[2][XBK][XSTR];
    __shared__ float Bs[2][XBK][XSTR];

    const int bm  = blockIdx.x;       // 0..799
    const int bn  = blockIdx.y;       // 0..1
    const int tid = threadIdx.x;
    const int tx = tid & 15;
    const int ty = tid >> 4;
    const int n0 = bn * XBN;

    const int am = tid >> 1;
    const int ak = (tid & 1) * 4;

    const float* arow = hcat + (size_t)(bm * XBM + am) * D_ + ak;
    const float* brow = W1 + (size_t)(n0 + am) * D_ + ak;

    float acc[8][8];
#pragma unroll
    for (int i = 0; i < 8; ++i)
#pragma unroll
        for (int j = 0; j < 8; ++j) acc[i][j] = 0.0f;

    {
        const float4 a = *(const float4*)(arow);
        const float4 b = *(const float4*)(brow);
        As[0][ak + 0][am] = a.x; As[0][ak + 1][am] = a.y;
        As[0][ak + 2][am] = a.z; As[0][ak + 3][am] = a.w;
        Bs[0][ak + 0][am] = b.x; Bs[0][ak + 1][am] = b.y;
        Bs[0][ak + 2][am] = b.z; Bs[0][ak + 3][am] = b.w;
    }
    __syncthreads();

    const int NIT = D_ / XBK;         // 32
    for (int it = 0; it < NIT; ++it) {
        const int cur = it & 1;
        const int kn  = (it + 1) * XBK;
        float4 na, nb;
        if (kn < D_) {
            na = *(const float4*)(arow + kn);
            nb = *(const float4*)(brow + kn);
        }
#pragma unroll
        for (int k = 0; k < XBK; ++k) {
            float a[8], bb[8];
            *(float4*)a        = *(const float4*)&As[cur][k][ty * 4];
            *(float4*)(a + 4)  = *(const float4*)&As[cur][k][64 + ty * 4];
            *(float4*)(bb)     = *(const float4*)&Bs[cur][k][tx * 4];
            *(float4*)(bb + 4) = *(const float4*)&Bs[cur][k][64 + tx * 4];
#pragma unroll
            for (int i = 0; i < 8; ++i)
#pragma unroll
                for (int j = 0; j < 8; ++j) acc[i][j] += a[i] * bb[j];
        }
        if (kn < D_) {
            const int nxt = cur ^ 1;
            As[nxt][ak + 0][am] = na.x; As[nxt][ak + 1][am] = na.y;
            As[nxt][ak + 2][am] = na.z; As[nxt][ak + 3][am] = na.w;
            Bs[nxt][ak + 0][am] = nb.x; Bs[nxt][ak + 1][am] = nb.y;
            Bs[nxt][ak + 2][am] = nb.z; Bs[nxt][ak + 3][am] = nb.w;
        }
        __syncthreads();
    }

    const int nb0i = n0 + tx * 4;
    const int nb1i = n0 + 64 + tx * 4;
    float bias[8];
#pragma unroll
    for (int j = 0; j < 4; ++j) {
        bias[j]     = b1[nb0i + j];
        bias[4 + j] = b1[nb1i + j];
    }
#pragma unroll
    for (int i = 0; i < 8; ++i) {
        const int row = bm * XBM + ((i < 4) ? (ty * 4 + i) : (64 + ty * 4 + i - 4));
        float* dst = h1 + (size_t)row * D_;
        float4 v0, v1;
        v0.x = leakyf_(acc[i][0] + bias[0]); v0.y = leakyf_(acc[i][1] + bias[1]);
        v0.z = leakyf_(acc[i][2] + bias[2]); v0.w = leakyf_(acc[i][3] + bias[3]);
        v1.x = leakyf_(acc[i][4] + bias[4]); v1.y = leakyf_(acc[i][5] + bias[5]);
        v1.z = leakyf_(acc[i][6] + bias[6]); v1.w = leakyf_(acc[i][7] + bias[7]);
        *(float4*)(dst + nb0i) = v0;
        *(float4*)(dst + nb1i) = v1;
    }
}

// ---------------------------------------------------------------------------
// K3b (RESTRUCTURED): MLP2 + tag projection.
// Round-7 diagnosis: part[8][6] (48 VGPR) lived across pass-2's k-loop ->
// VGPR 136 (> the 128 cliff) -> 2 waves/SIMD, occupancy 9%, VALU 38%.
// Fix: fold tags PER PASS, PER ROW-HALF (part[4][6] = 24 regs, epilogue-only
// lifetime), reduce via quad-DPP (VALU) + 2 shfl_xor, accumulate into LDS
// lg_s[128][6] (tx==0 lanes, disjoint rows; pass-2 += is in-thread ordered).
// k-loop live set back to ~100 regs; __launch_bounds__(256,4) enforces <=128.
// ---------------------------------------------------------------------------
__global__ __launch_bounds__(256, 4) void mlp2tag(
    const float* __restrict__ h1,
    const float* __restrict__ W2, const float* __restrict__ b2,
    const float* __restrict__ Wt, const float* __restrict__ bt,
    float* __restrict__ logits)
{
    __shared__ float As[2][XBK][XSTR];
    __shared__ float Bs[2][XBK][XSTR];
    __shared__ float Wt_s[T_][D_ + 2];
    __shared__ float b2_s[D_];
    __shared__ float bt_s[T_];
    __shared__ float lg_s[XBM][T_];     // per-row tag accumulator

    const int bm  = blockIdx.x;       // 0..799
    const int tid = threadIdx.x;
    const int tx = tid & 15;
    const int ty = tid >> 4;

    for (int i = tid; i < T_ * D_; i += 256) Wt_s[i >> 8][i & 255] = Wt[i];
    b2_s[tid] = b2[tid];
    if (tid < T_) bt_s[tid] = bt[tid];
    for (int i = tid; i < XBM * T_; i += 256) ((float*)lg_s)[i] = 0.0f;

    const int am = tid >> 1;
    const int ak = (tid & 1) * 4;

    const float* arow = h1 + (size_t)(bm * XBM + am) * D_ + ak;

    for (int n0t = 0; n0t < 2; ++n0t) {
        const int n0 = n0t * XBN;
        const float* brow = W2 + (size_t)(n0 + am) * D_ + ak;

        float acc[8][8];
#pragma unroll
        for (int i = 0; i < 8; ++i)
#pragma unroll
            for (int j = 0; j < 8; ++j) acc[i][j] = 0.0f;

        // prologue (the barrier also orders Wt_s/b2_s/lg_s staging)
        {
            const float4 a = *(const float4*)(arow);
            const float4 b = *(const float4*)(brow);
            As[0][ak + 0][am] = a.x; As[0][ak + 1][am] = a.y;
            As[0][ak + 2][am] = a.z; As[0][ak + 3][am] = a.w;
            Bs[0][ak + 0][am] = b.x; Bs[0][ak + 1][am] = b.y;
            Bs[0][ak + 2][am] = b.z; Bs[0][ak + 3][am] = b.w;
        }
        __syncthreads();

        const int NIT = D_ / XBK;     // 32
        for (int it = 0; it < NIT; ++it) {
            const int cur = it & 1;
            const int kn  = (it + 1) * XBK;
            float4 na, nb;
            if (kn < D_) {
                na = *(const float4*)(arow + kn);
                nb = *(const float4*)(brow + kn);
            }
#pragma unroll
            for (int k = 0; k < XBK; ++k) {
                float a[8], bb[8];
                *(float4*)a        = *(const float4*)&As[cur][k][ty * 4];
                *(float4*)(a + 4)  = *(const float4*)&As[cur][k][64 + ty * 4];
                *(float4*)(bb)     = *(const float4*)&Bs[cur][k][tx * 4];
                *(float4*)(bb + 4) = *(const float4*)&Bs[cur][k][64 + tx * 4];
#pragma unroll
                for (int i = 0; i < 8; ++i)
#pragma unroll
                    for (int j = 0; j < 8; ++j) acc[i][j] += a[i] * bb[j];
            }
            if (kn < D_) {
                const int nxt = cur ^ 1;
                As[nxt][ak + 0][am] = na.x; As[nxt][ak + 1][am] = na.y;
                As[nxt][ak + 2][am] = na.z; As[nxt][ak + 3][am] = na.w;
                Bs[nxt][ak + 0][am] = nb.x; Bs[nxt][ak + 1][am] = nb.y;
                Bs[nxt][ak + 2][am] = nb.z; Bs[nxt][ak + 3][am] = nb.w;
            }
            __syncthreads();
        }

        // per-pass epilogue, per row-half: h2 = leaky(acc + b2) -> tag fold
#pragma unroll
        for (int hf = 0; hf < 2; ++hf) {
            float part[4][T_];
#pragma unroll
            for (int i = 0; i < 4; ++i)
#pragma unroll
                for (int jt = 0; jt < T_; ++jt) part[i][jt] = 0.0f;

#pragma unroll
            for (int j = 0; j < 8; ++j) {
                const int col = n0 + ((j < 4) ? (tx * 4 + j) : (64 + tx * 4 + j - 4));
                const float bv = b2_s[col];
#pragma unroll
                for (int i = 0; i < 4; ++i) {
                    const float h2v = leakyf_(acc[hf * 4 + i][j] + bv);
#pragma unroll
                    for (int jt = 0; jt < T_; ++jt)
                        part[i][jt] += h2v * Wt_s[jt][col];
                }
            }

            // 16-lane reduce: quad-DPP (VALU) + shfl_xor 4, 8 (LDS halved)
#pragma unroll
            for (int i = 0; i < 4; ++i)
#pragma unroll
                for (int jt = 0; jt < T_; ++jt) {
                    float v = part[i][jt];
                    v = dpp_add_<0xB1>(v);
                    v = dpp_add_<0x4E>(v);
                    v += __shfl_xor(v, 4, 16);
                    v += __shfl_xor(v, 8, 16);
                    part[i][jt] = v;
                }

            if (tx == 0) {
#pragma unroll
                for (int i = 0; i < 4; ++i) {
                    const int r = (hf == 0) ? (ty * 4 + i) : (64 + ty * 4 + i);
#pragma unroll
                    for (int jt = 0; jt < T_; ++jt)
                        lg_s[r][jt] += part[i][jt];
                }
            }
        }
    }

    __syncthreads();
    if (tid < XBM) {
        const int row = bm * XBM + tid;
#pragma unroll
        for (int jt = 0; jt < T_; ++jt)
            logits[(size_t)row * T_ + jt] = leakyf_(lg_s[tid][jt] + bt_s[jt]);
    }
}

// ---------------------------------------------------------------------------
// K3 (FALLBACK): fused MLP — round-3 measured version, used only if ws can't
// hold h1 (never expected given measured ws >= 249 MB).
// ---------------------------------------------------------------------------
#define BM 64
#define BN 128
#define BK 16
#define ASTR 68
#define BSTR 132
#define S1T 68   // h1T row stride

__global__ __launch_bounds__(256) void fused_mlp(
    const float* __restrict__ hcat,
    const float* __restrict__ W1, const float* __restrict__ b1,
    const float* __restrict__ W2, const float* __restrict__ b2,
    const float* __restrict__ Wt, const float* __restrict__ bt,
    float* __restrict__ logits)
{
    __shared__ float As[BK][ASTR];
    __shared__ float Bs[BK][BSTR];
    __shared__ float h1T[BN][S1T];
    __shared__ float Wt_s[T_][D_ + 2];
    __shared__ float b1_s[D_], b2_s[D_], bt_s[T_];

    const int tid  = threadIdx.x;
    const int row0 = blockIdx.x * BM;

    for (int i = tid; i < T_ * D_; i += 256) Wt_s[i >> 8][i & 255] = Wt[i];
    b1_s[tid] = b1[tid];
    b2_s[tid] = b2[tid];
    if (tid < T_) bt_s[tid] = bt[tid];

    const int tx = tid & 15;
    const int ty = tid >> 4;
    const int lrow = tid >> 2;
    const int lk   = (tid & 3) * 4;

    const float* arow = hcat + (size_t)(row0 + lrow) * D_ + lk;

    float acc2[2][4][8];
#pragma unroll
    for (int q = 0; q < 2; ++q)
#pragma unroll
        for (int i = 0; i < 4; ++i)
#pragma unroll
            for (int j = 0; j < 8; ++j) acc2[q][i][j] = 0.0f;

    for (int n0t = 0; n0t < 2; ++n0t) {
        const int n0 = n0t * BN;

        float acc1[4][8];
#pragma unroll
        for (int i = 0; i < 4; ++i)
#pragma unroll
            for (int j = 0; j < 8; ++j) acc1[i][j] = 0.0f;

        for (int k0 = 0; k0 < D_; k0 += BK) {
            {
                const float4 v = *(const float4*)(arow + k0);
                As[lk + 0][lrow] = v.x; As[lk + 1][lrow] = v.y;
                As[lk + 2][lrow] = v.z; As[lk + 3][lrow] = v.w;
            }
#pragma unroll
            for (int p = 0; p < 2; ++p) {
                const int n = p * 64 + lrow;
                const float4 v = *(const float4*)(W1 + (size_t)(n0 + n) * D_ + k0 + lk);
                Bs[lk + 0][n] = v.x; Bs[lk + 1][n] = v.y;
                Bs[lk + 2][n] = v.z; Bs[lk + 3][n] = v.w;
            }
            __syncthreads();
#pragma unroll
            for (int k = 0; k < BK; ++k) {
                float a[4], bb[8];
                *(float4*)a        = *(const float4*)&As[k][ty * 4];
                *(float4*)(bb)     = *(const float4*)&Bs[k][tx * 4];
                *(float4*)(bb + 4) = *(const float4*)&Bs[k][64 + tx * 4];
#pragma unroll
                for (int i = 0; i < 4; ++i)
#pragma unroll
                    for (int j = 0; j < 8; ++j) acc1[i][j] += a[i] * bb[j];
            }
            __syncthreads();
        }

#pragma unroll
        for (int j = 0; j < 8; ++j) {
            const int nl = (j < 4) ? (tx * 4 + j) : (64 + tx * 4 + j - 4);
            const float bv = b1_s[n0 + nl];
            float4 v;
            v.x = leakyf_(acc1[0][j] + bv);
            v.y = leakyf_(acc1[1][j] + bv);
            v.z = leakyf_(acc1[2][j] + bv);
            v.w = leakyf_(acc1[3][j] + bv);
            *(float4*)&h1T[nl][ty * 4] = v;
        }
        __syncthreads();

#pragma unroll
        for (int n2t = 0; n2t < 2; ++n2t) {
            for (int kc = 0; kc < BN; kc += BK) {
#pragma unroll
                for (int p = 0; p < 2; ++p) {
                    const int n = p * 64 + lrow;
                    const float4 v = *(const float4*)(W2 + (size_t)(n2t * BN + n) * D_ + n0 + kc + lk);
                    Bs[lk + 0][n] = v.x; Bs[lk + 1][n] = v.y;
                    Bs[lk + 2][n] = v.z; Bs[lk + 3][n] = v.w;
                }
                __syncthreads();
#pragma unroll
                for (int k = 0; k < BK; ++k) {
                    float a[4], bb[8];
                    *(float4*)a        = *(const float4*)&h1T[kc + k][ty * 4];
                    *(float4*)(bb)     = *(const float4*)&Bs[k][tx * 4];
                    *(float4*)(bb + 4) = *(const float4*)&Bs[k][64 + tx * 4];
#pragma unroll
                    for (int i = 0; i < 4; ++i)
#pragma unroll
                        for (int j = 0; j < 8; ++j) acc2[n2t][i][j] += a[i] * bb[j];
                }
                __syncthreads();
            }
        }
    }

    float part[4][T_];
#pragma unroll
    for (int i = 0; i < 4; ++i)
#pragma unroll
        for (int jt = 0; jt < T_; ++jt) part[i][jt] = 0.0f;

#pragma unroll
    for (int q = 0; q < 2; ++q)
#pragma unroll
        for (int j = 0; j < 8; ++j) {
            const int n = q * BN + ((j < 4) ? (tx * 4 + j) : (64 + tx * 4 + j - 4));
            const float bv = b2_s[n];
            float h2v[4];
#pragma unroll
            for (int i = 0; i < 4; ++i) h2v[i] = leakyf_(acc2[q][i][j] + bv);
#pragma unroll
            for (int jt = 0; jt < T_; ++jt) {
                const float wv = Wt_s[jt][n];
#pragma unroll
                for (int i = 0; i < 4; ++i) part[i][jt] += h2v[i] * wv;
            }
        }

#pragma unroll
    for (int m = 1; m <= 8; m <<= 1)
#pragma unroll
        for (int i = 0; i < 4; ++i)
#pragma unroll
            for (int jt = 0; jt < T_; ++jt)
                part[i][jt] += __shfl_xor(part[i][jt], m, 16);

    if (tx == 0) {
#pragma unroll
        for (int i = 0; i < 4; ++i) {
            const int m = row0 + ty * 4 + i;
#pragma unroll
            for (int jt = 0; jt < T_; ++jt)
                logits[(size_t)m * T_ + jt] = leakyf_(part[i][jt] + bt_s[jt]);
        }
    }
}

// ---------------------------------------------------------------------------
// K4: Viterbi per sample — unchanged.
// ---------------------------------------------------------------------------
__global__ __launch_bounds__(64) void viterbi_kernel(
    const float* __restrict__ logits, const float* __restrict__ trans,
    float* __restrict__ out)
{
    const int b = blockIdx.x;
    const int lane = threadIdx.x;

    __shared__ unsigned char bp[L_][8];
    __shared__ int path_s[L_];

    float tr[T_];
    if (lane < T_) {
#pragma unroll
        for (int i = 0; i < T_; ++i) tr[i] = trans[i * T_ + lane];
    }
    const float* lg = logits + (size_t)b * L_ * T_;
    float prev = (lane < T_) ? lg[lane] : -1e30f;

    for (int t = 1; t < L_; ++t) {
        float m = -1e30f; int arg = 0;
#pragma unroll
        for (int i = 0; i < T_; ++i) {
            const float v = __shfl(prev, i, 64) + tr[i];
            if (v > m) { m = v; arg = i; }
        }
        const float obs = (lane < T_) ? lg[t * T_ + lane] : 0.0f;
        prev = obs + m;
        if (lane < T_) bp[t][lane] = (unsigned char)arg;
    }
    __syncthreads();

    float best = __shfl(prev, 0, 64); int tag = 0;
#pragma unroll
    for (int jj = 1; jj < T_; ++jj) {
        const float v = __shfl(prev, jj, 64);
        if (v > best) { best = v; tag = jj; }
    }
    if (lane == 0) {
        out[b] = best;
        path_s[L_ - 1] = tag;
        for (int t = L_ - 1; t >= 1; --t) {
            tag = bp[t][tag];
            path_s[t - 1] = tag;
        }
    }
    __syncthreads();
    for (int i = lane; i < L_; i += 64)
        out[B_ + (size_t)b * L_ + i] = (float)path_s[i];
}

// ---------------------------------------------------------------------------
extern "C" void kernel_launch(void* const* d_in, const int* in_sizes, int n_in,
                              void* d_out, int out_size, void* d_ws, size_t ws_size,
                              hipStream_t stream)
{
    (void)in_sizes; (void)n_in; (void)out_size;

    const int*   sent  = (const int*)  d_in[0];
    const float* emb   = (const float*)d_in[2];
    const float* Wih_f = (const float*)d_in[3];
    const float* Whh_f = (const float*)d_in[4];
    const float* bih_f = (const float*)d_in[5];
    const float* bhh_f = (const float*)d_in[6];
    const float* Wih_b = (const float*)d_in[7];
    const float* Whh_b = (const float*)d_in[8];
    const float* bih_b = (const float*)d_in[9];
    const float* bhh_b = (const float*)d_in[10];
    const float* W1    = (const float*)d_in[11];
    const float* b1    = (const float*)d_in[12];
    const float* W2    = (const float*)d_in[13];
    const float* b2    = (const float*)d_in[14];
    const float* Wt    = (const float*)d_in[15];
    const float* bt    = (const float*)d_in[16];
    const float* trans = (const float*)d_in[17];

    float* ws = (float*)d_ws;
    const size_t HCAT_E = (size_t)B_ * L_ * D_;     // 26,214,400 floats
    const size_t LG_E   = (size_t)B_ * L_ * T_;     //    614,400
    const size_t ST_E   = (size_t)2 * B_ * 2 * H_;  //    262,144
    const size_t H1_E   = HCAT_E;                   // h1 is B*L*D too
    float* hcat   = ws;
    float* logits = ws + HCAT_E;
    float* state  = logits + LG_E;
    float* xgc    = state + ST_E;

    // Adaptive time-chunk so the xg staging buffer fits in ws_size.
    // (measured: ws in [249,312) MB -> 3 chunks; P-table path infeasible)
    const size_t base  = HCAT_E + LG_E + ST_E;      // ~108 MB
    const size_t per_t = (size_t)2 * B_ * G4H_;     // 524,288 floats per timestep
    const size_t ws_f  = ws_size / sizeof(float);
    long long avail = (long long)ws_f - (long long)base;
    int Tc = (avail > 0) ? (int)(avail / (long long)per_t) : 0;
    if (Tc < 1)  Tc = 1;
    if (Tc > L_) Tc = L_;

    float* out = (float*)d_out;

    for (int c0 = 0; c0 < L_; c0 += Tc) {
        const int tc = (L_ - c0 < Tc) ? (L_ - c0) : Tc;
        gemm_xg_chunk<<<dim3(8 * tc, 4), 256, 0, stream>>>(
            sent, emb, Wih_f, Wih_b, bih_f, bhh_f, bih_b, bhh_b, xgc, c0, tc);
        lstm_scan_chunk<<<256, 512, 0, stream>>>(
            xgc, Whh_f, Whh_b, state, hcat, c0, tc);
    }

    if (avail >= (long long)H1_E) {
        // h1 aliases xgc: the LSTM phase is done with xgc before mlp1 runs.
        float* h1 = xgc;
        mlp1_gemm<<<dim3((B_ * L_) / XBM, 2), 256, 0, stream>>>(hcat, W1, b1, h1);
        mlp2tag<<<(B_ * L_) / XBM, 256, 0, stream>>>(h1, W2, b2, Wt, bt, logits);
    } else {
        fused_mlp<<<(B_ * L_) / BM, 256, 0, stream>>>(
            hcat, W1, b1, W2, b2, Wt, bt, logits);
    }
    viterbi_kernel<<<B_, 64, 0, stream>>>(logits, trans, out);
}

// Round 9
// 1810.295 us; speedup vs baseline: 1.1300x; 1.1300x over previous
//
#include <hip/hip_runtime.h>
#include <cmath>

// Problem constants
#define B_   512
#define L_   200
#define V_   50000
#define E_   256
#define H_   128     // per-direction hidden
#define G4H_ 512     // 4*H
#define D_   256     // 2*H
#define T_   6

__device__ __forceinline__ float sigmoidf_(float x) { return 1.0f / (1.0f + __expf(-x)); }
__device__ __forceinline__ float leakyf_(float x)   { return x >= 0.0f ? x : 0.01f * x; }

// DPP quad-perm add (VALU pipe — NOT ds_bpermute/LDS). CTRL: xor1=0xB1, xor2=0x4E.
template<int CTRL>
__device__ __forceinline__ float dpp_add_(float x) {
    const int m = __builtin_amdgcn_mov_dpp(__float_as_int(x), CTRL, 0xF, 0xF, true);
    return x + __int_as_float(m);
}

// ---------------------------------------------------------------------------
// K1: xg GEMM, 128x128 tile, 8x8 micro-tile, BK=8, ping-pong double buffer.
// Plain __launch_bounds__(256) — rounds 3-7 measured config (~220 us/chunk).
// Round-8 lesson: forcing (256,4) risks a spill cascade (mlp2tag: VGPR 64,
// 0.93 GB scratch traffic). Never set an occupancy floor the live set can't meet.
// ---------------------------------------------------------------------------
#define XBM 128
#define XBN 128
#define XBK 8
#define XSTR 132

__global__ __launch_bounds__(256) void gemm_xg_chunk(
    const int* __restrict__ sent, const float* __restrict__ emb,
    const float* __restrict__ Wf, const float* __restrict__ Wb,
    const float* __restrict__ bihf, const float* __restrict__ bhhf,
    const float* __restrict__ bihb, const float* __restrict__ bhhb,
    float* __restrict__ xgc, int c0, int tc)
{
    __shared__ float As[2][XBK][XSTR];
    __shared__ float Bs[2][XBK][XSTR];
    __shared__ int   tok[XBM];

    const int bm  = blockIdx.x;       // 0 .. 8*tc-1
    const int bn  = blockIdx.y;       // 0..3 (N=512 per dir)
    const int tid = threadIdx.x;
    const int half = B_ * tc;         // rows per direction
    const int dir  = (bm * XBM) >= half;  // uniform (B*tc % 128 == 0)

    if (tid < XBM) {
        const int vm  = bm * XBM + tid;
        const int rem = vm - dir * half;
        const int b   = rem / tc;
        const int ti  = rem - b * tc;
        const int s   = c0 + ti;
        const int t   = dir ? (L_ - 1 - s) : s;
        tok[tid] = sent[b * L_ + t];
    }
    __syncthreads();

    const int tx = tid & 15;          // n quad: tx*4 and 64+tx*4
    const int ty = tid >> 4;          // m quad: ty*4 and 64+ty*4
    const int n0 = bn * XBN;

    const float* W   = dir ? Wb   : Wf;
    const float* bih = dir ? bihb : bihf;
    const float* bhh = dir ? bhhb : bhhf;

    const int am = tid >> 1;          // staging row 0..127
    const int ak = (tid & 1) * 4;     // staging k 0 or 4

    const float* arow = emb + (size_t)tok[am] * E_ + ak;
    const float* brow = W + (size_t)(n0 + am) * E_ + ak;

    float acc[8][8];
#pragma unroll
    for (int i = 0; i < 8; ++i)
#pragma unroll
        for (int j = 0; j < 8; ++j) acc[i][j] = 0.0f;

    // prologue: stage slice 0
    {
        const float4 a = *(const float4*)(arow);
        const float4 b = *(const float4*)(brow);
        As[0][ak + 0][am] = a.x; As[0][ak + 1][am] = a.y;
        As[0][ak + 2][am] = a.z; As[0][ak + 3][am] = a.w;
        Bs[0][ak + 0][am] = b.x; Bs[0][ak + 1][am] = b.y;
        Bs[0][ak + 2][am] = b.z; Bs[0][ak + 3][am] = b.w;
    }
    __syncthreads();

    const int NIT = E_ / XBK;         // 32
    for (int it = 0; it < NIT; ++it) {
        const int cur = it & 1;
        const int kn  = (it + 1) * XBK;
        float4 na, nb;
        if (kn < E_) {
            na = *(const float4*)(arow + kn);
            nb = *(const float4*)(brow + kn);
        }
#pragma unroll
        for (int k = 0; k < XBK; ++k) {
            float a[8], bb[8];
            *(float4*)a        = *(const float4*)&As[cur][k][ty * 4];
            *(float4*)(a + 4)  = *(const float4*)&As[cur][k][64 + ty * 4];
            *(float4*)(bb)     = *(const float4*)&Bs[cur][k][tx * 4];
            *(float4*)(bb + 4) = *(const float4*)&Bs[cur][k][64 + tx * 4];
#pragma unroll
            for (int i = 0; i < 8; ++i)
#pragma unroll
                for (int j = 0; j < 8; ++j) acc[i][j] += a[i] * bb[j];
        }
        if (kn < E_) {
            const int nxt = cur ^ 1;
            As[nxt][ak + 0][am] = na.x; As[nxt][ak + 1][am] = na.y;
            As[nxt][ak + 2][am] = na.z; As[nxt][ak + 3][am] = na.w;
            Bs[nxt][ak + 0][am] = nb.x; Bs[nxt][ak + 1][am] = nb.y;
            Bs[nxt][ak + 2][am] = nb.z; Bs[nxt][ak + 3][am] = nb.w;
        }
        __syncthreads();
    }

    // epilogue: bias + store.
    const int nb0i = n0 + tx * 4;
    const int nb1i = n0 + 64 + tx * 4;
    float bias[8];
#pragma unroll
    for (int j = 0; j < 4; ++j) {
        bias[j]     = bih[nb0i + j] + bhh[nb0i + j];
        bias[4 + j] = bih[nb1i + j] + bhh[nb1i + j];
    }
#pragma unroll
    for (int i = 0; i < 8; ++i) {
        const int row = bm * XBM + ((i < 4) ? (ty * 4 + i) : (64 + ty * 4 + i - 4));
        float* dst = xgc + (size_t)row * G4H_;
        float4 v0, v1;
        v0.x = acc[i][0] + bias[0]; v0.y = acc[i][1] + bias[1];
        v0.z = acc[i][2] + bias[2]; v0.w = acc[i][3] + bias[3];
        v1.x = acc[i][4] + bias[4]; v1.y = acc[i][5] + bias[5];
        v1.z = acc[i][6] + bias[6]; v1.w = acc[i][7] + bias[7];
        *(float4*)(dst + nb0i) = v0;
        *(float4*)(dst + nb1i) = v1;
    }
}

// ---------------------------------------------------------------------------
// K2 (v4, unchanged): LSTM scan, split-K + DPP quad reduce, one barrier/step.
// ---------------------------------------------------------------------------
__global__ __launch_bounds__(512, 2) void lstm_scan_chunk(
    const float* __restrict__ xgc,
    const float* __restrict__ Whh_f, const float* __restrict__ Whh_b,
    float* __restrict__ state, float* __restrict__ hcat, int c0, int tc)
{
    const int wg  = blockIdx.x;      // 0..255
    const int dir = wg >> 7;
    const int b0  = (wg & 127) * 4;  // 4 samples per wg
    const int tid = threadIdx.x;     // 0..511

    const int q  = tid & 3;          // k-quarter AND this lane's sample
    const int g2 = tid >> 2;         // hidden j / gate-group 0..127

    const float* Whh = dir ? Whh_b : Whh_f;

    float w[4][32];
#pragma unroll
    for (int p = 0; p < 4; ++p) {
        const float* wr = Whh + (size_t)(g2 + 128 * p) * H_ + q * 32;
#pragma unroll
        for (int kk = 0; kk < 32; kk += 4) {
            const float4 v = *(const float4*)(wr + kk);
            w[p][kk] = v.x; w[p][kk + 1] = v.y; w[p][kk + 2] = v.z; w[p][kk + 3] = v.w;
        }
    }

    __shared__ float hbuf[2][4 * 132];   // [parity][quarter q'*132 + kk*4 + s]

    float c, hval;
    if (c0 == 0) {
        hval = 0.0f;
        c    = 0.0f;
    } else {
        hval = state[((size_t)(dir * B_ + b0 + q) * 2 + 0) * H_ + g2];
        c    = state[((size_t)(dir * B_ + b0 + q) * 2 + 1) * H_ + g2];
    }
    hbuf[0][(g2 >> 5) * 132 + (g2 & 31) * 4 + q] = hval;

    const int t0    = dir ? (L_ - 1 - c0) : c0;
    const int hstep = dir ? -D_ : D_;

    const float* xq = xgc + ((size_t)(dir * B_ + b0 + q) * tc) * G4H_ + g2;
    float* hp = hcat + ((size_t)(b0 + q) * L_ + t0) * D_ + dir * H_ + g2;

    __syncthreads();

    for (int t = 0; t < tc; ++t) {
        const int par = t & 1;
        const float* hq = &hbuf[par][q * 132];

        float xg[4];
#pragma unroll
        for (int p = 0; p < 4; ++p) xg[p] = xq[128 * p];
        xq += G4H_;

        float acc[4][4];
#pragma unroll
        for (int p = 0; p < 4; ++p)
#pragma unroll
            for (int s = 0; s < 4; ++s) acc[p][s] = 0.0f;

#pragma unroll
        for (int kk = 0; kk < 32; ++kk) {
            const float4 hv = *(const float4*)(hq + kk * 4);
#pragma unroll
            for (int p = 0; p < 4; ++p) {
                acc[p][0] += w[p][kk] * hv.x;
                acc[p][1] += w[p][kk] * hv.y;
                acc[p][2] += w[p][kk] * hv.z;
                acc[p][3] += w[p][kk] * hv.w;
            }
        }

#pragma unroll
        for (int p = 0; p < 4; ++p)
#pragma unroll
            for (int s = 0; s < 4; ++s) {
                float v = acc[p][s];
                v = dpp_add_<0xB1>(v);
                v = dpp_add_<0x4E>(v);
                acc[p][s] = v;
            }

        float gi = acc[0][0], gf = acc[1][0], gg = acc[2][0], go = acc[3][0];
        if (q == 1) { gi = acc[0][1]; gf = acc[1][1]; gg = acc[2][1]; go = acc[3][1]; }
        if (q == 2) { gi = acc[0][2]; gf = acc[1][2]; gg = acc[2][2]; go = acc[3][2]; }
        if (q == 3) { gi = acc[0][3]; gf = acc[1][3]; gg = acc[2][3]; go = acc[3][3]; }
        gi += xg[0]; gf += xg[1]; gg += xg[2]; go += xg[3];

        c    = sigmoidf_(gf) * c + sigmoidf_(gi) * tanhf(gg);
        hval = sigmoidf_(go) * tanhf(c);

        hbuf[par ^ 1][(g2 >> 5) * 132 + (g2 & 31) * 4 + q] = hval;
        hp[0] = hval;
        hp += hstep;
        __syncthreads();
    }

    state[((size_t)(dir * B_ + b0 + q) * 2 + 0) * H_ + g2] = hval;
    state[((size_t)(dir * B_ + b0 + q) * 2 + 1) * H_ + g2] = c;
}

// ---------------------------------------------------------------------------
// K3a: MLP1, 128x128/8x8 GEMM, plain bounds (round-7 measured ~235 us).
// h1 = leaky(hcat @ W1^T + b1). Grid (800, 2).
// ---------------------------------------------------------------------------
__global__ __launch_bounds__(256) void mlp1_gemm(
    const float* __restrict__ hcat,
    const float* __restrict__ W1, const float* __restrict__ b1,
    float* __restrict__ h1)
{
    __shared__ float As[2][XBK][XSTR];
    __shared__ float Bs[2][XBK][XSTR];

    const int bm  = blockIdx.x;       // 0..799
    const int bn  = blockIdx.y;       // 0..1
    const int tid = threadIdx.x;
    const int tx = tid & 15;
    const int ty = tid >> 4;
    const int n0 = bn * XBN;

    const int am = tid >> 1;
    const int ak = (tid & 1) * 4;

    const float* arow = hcat + (size_t)(bm * XBM + am) * D_ + ak;
    const float* brow = W1 + (size_t)(n0 + am) * D_ + ak;

    float acc[8][8];
#pragma unroll
    for (int i = 0; i < 8; ++i)
#pragma unroll
        for (int j = 0; j < 8; ++j) acc[i][j] = 0.0f;

    {
        const float4 a = *(const float4*)(arow);
        const float4 b = *(const float4*)(brow);
        As[0][ak + 0][am] = a.x; As[0][ak + 1][am] = a.y;
        As[0][ak + 2][am] = a.z; As[0][ak + 3][am] = a.w;
        Bs[0][ak + 0][am] = b.x; Bs[0][ak + 1][am] = b.y;
        Bs[0][ak + 2][am] = b.z; Bs[0][ak + 3][am] = b.w;
    }
    __syncthreads();

    const int NIT = D_ / XBK;         // 32
    for (int it = 0; it < NIT; ++it) {
        const int cur = it & 1;
        const int kn  = (it + 1) * XBK;
        float4 na, nb;
        if (kn < D_) {
            na = *(const float4*)(arow + kn);
            nb = *(const float4*)(brow + kn);
        }
#pragma unroll
        for (int k = 0; k < XBK; ++k) {
            float a[8], bb[8];
            *(float4*)a        = *(const float4*)&As[cur][k][ty * 4];
            *(float4*)(a + 4)  = *(const float4*)&As[cur][k][64 + ty * 4];
            *(float4*)(bb)     = *(const float4*)&Bs[cur][k][tx * 4];
            *(float4*)(bb + 4) = *(const float4*)&Bs[cur][k][64 + tx * 4];
#pragma unroll
            for (int i = 0; i < 8; ++i)
#pragma unroll
                for (int j = 0; j < 8; ++j) acc[i][j] += a[i] * bb[j];
        }
        if (kn < D_) {
            const int nxt = cur ^ 1;
            As[nxt][ak + 0][am] = na.x; As[nxt][ak + 1][am] = na.y;
            As[nxt][ak + 2][am] = na.z; As[nxt][ak + 3][am] = na.w;
            Bs[nxt][ak + 0][am] = nb.x; Bs[nxt][ak + 1][am] = nb.y;
            Bs[nxt][ak + 2][am] = nb.z; Bs[nxt][ak + 3][am] = nb.w;
        }
        __syncthreads();
    }

    const int nb0i = n0 + tx * 4;
    const int nb1i = n0 + 64 + tx * 4;
    float bias[8];
#pragma unroll
    for (int j = 0; j < 4; ++j) {
        bias[j]     = b1[nb0i + j];
        bias[4 + j] = b1[nb1i + j];
    }
#pragma unroll
    for (int i = 0; i < 8; ++i) {
        const int row = bm * XBM + ((i < 4) ? (ty * 4 + i) : (64 + ty * 4 + i - 4));
        float* dst = h1 + (size_t)row * D_;
        float4 v0, v1;
        v0.x = leakyf_(acc[i][0] + bias[0]); v0.y = leakyf_(acc[i][1] + bias[1]);
        v0.z = leakyf_(acc[i][2] + bias[2]); v0.w = leakyf_(acc[i][3] + bias[3]);
        v1.x = leakyf_(acc[i][4] + bias[4]); v1.y = leakyf_(acc[i][5] + bias[5]);
        v1.z = leakyf_(acc[i][6] + bias[6]); v1.w = leakyf_(acc[i][7] + bias[7]);
        *(float4*)(dst + nb0i) = v0;
        *(float4*)(dst + nb1i) = v1;
    }
}

// ---------------------------------------------------------------------------
// K3b: MLP2 + tag projection — round-8 STRUCTURE (per-pass tag fold, LDS
// accumulator) with PLAIN __launch_bounds__(256). The structure fixed
// round-7's cross-k-loop part[8][6] liveness (136 VGPR); the removed ",4"
// bound fixes round-8's spill cascade (VGPR 64, 0.93 GB scratch traffic).
// Expected natural allocation ~120-128 (k-loop live ~110).
// ---------------------------------------------------------------------------
__global__ __launch_bounds__(256) void mlp2tag(
    const float* __restrict__ h1,
    const float* __restrict__ W2, const float* __restrict__ b2,
    const float* __restrict__ Wt, const float* __restrict__ bt,
    float* __restrict__ logits)
{
    __shared__ float As[2][XBK][XSTR];
    __shared__ float Bs[2][XBK][XSTR];
    __shared__ float Wt_s[T_][D_ + 2];
    __shared__ float b2_s[D_];
    __shared__ float bt_s[T_];
    __shared__ float lg_s[XBM][T_];     // per-row tag accumulator

    const int bm  = blockIdx.x;       // 0..799
    const int tid = threadIdx.x;
    const int tx = tid & 15;
    const int ty = tid >> 4;

    for (int i = tid; i < T_ * D_; i += 256) Wt_s[i >> 8][i & 255] = Wt[i];
    b2_s[tid] = b2[tid];
    if (tid < T_) bt_s[tid] = bt[tid];
    for (int i = tid; i < XBM * T_; i += 256) ((float*)lg_s)[i] = 0.0f;

    const int am = tid >> 1;
    const int ak = (tid & 1) * 4;

    const float* arow = h1 + (size_t)(bm * XBM + am) * D_ + ak;

    for (int n0t = 0; n0t < 2; ++n0t) {
        const int n0 = n0t * XBN;
        const float* brow = W2 + (size_t)(n0 + am) * D_ + ak;

        float acc[8][8];
#pragma unroll
        for (int i = 0; i < 8; ++i)
#pragma unroll
            for (int j = 0; j < 8; ++j) acc[i][j] = 0.0f;

        // prologue (the barrier also orders Wt_s/b2_s/lg_s staging)
        {
            const float4 a = *(const float4*)(arow);
            const float4 b = *(const float4*)(brow);
            As[0][ak + 0][am] = a.x; As[0][ak + 1][am] = a.y;
            As[0][ak + 2][am] = a.z; As[0][ak + 3][am] = a.w;
            Bs[0][ak + 0][am] = b.x; Bs[0][ak + 1][am] = b.y;
            Bs[0][ak + 2][am] = b.z; Bs[0][ak + 3][am] = b.w;
        }
        __syncthreads();

        const int NIT = D_ / XBK;     // 32
        for (int it = 0; it < NIT; ++it) {
            const int cur = it & 1;
            const int kn  = (it + 1) * XBK;
            float4 na, nb;
            if (kn < D_) {
                na = *(const float4*)(arow + kn);
                nb = *(const float4*)(brow + kn);
            }
#pragma unroll
            for (int k = 0; k < XBK; ++k) {
                float a[8], bb[8];
                *(float4*)a        = *(const float4*)&As[cur][k][ty * 4];
                *(float4*)(a + 4)  = *(const float4*)&As[cur][k][64 + ty * 4];
                *(float4*)(bb)     = *(const float4*)&Bs[cur][k][tx * 4];
                *(float4*)(bb + 4) = *(const float4*)&Bs[cur][k][64 + tx * 4];
#pragma unroll
                for (int i = 0; i < 8; ++i)
#pragma unroll
                    for (int j = 0; j < 8; ++j) acc[i][j] += a[i] * bb[j];
            }
            if (kn < D_) {
                const int nxt = cur ^ 1;
                As[nxt][ak + 0][am] = na.x; As[nxt][ak + 1][am] = na.y;
                As[nxt][ak + 2][am] = na.z; As[nxt][ak + 3][am] = na.w;
                Bs[nxt][ak + 0][am] = nb.x; Bs[nxt][ak + 1][am] = nb.y;
                Bs[nxt][ak + 2][am] = nb.z; Bs[nxt][ak + 3][am] = nb.w;
            }
            __syncthreads();
        }

        // per-pass epilogue, per row-half: h2 = leaky(acc + b2) -> tag fold
#pragma unroll
        for (int hf = 0; hf < 2; ++hf) {
            float part[4][T_];
#pragma unroll
            for (int i = 0; i < 4; ++i)
#pragma unroll
                for (int jt = 0; jt < T_; ++jt) part[i][jt] = 0.0f;

#pragma unroll
            for (int j = 0; j < 8; ++j) {
                const int col = n0 + ((j < 4) ? (tx * 4 + j) : (64 + tx * 4 + j - 4));
                const float bv = b2_s[col];
#pragma unroll
                for (int i = 0; i < 4; ++i) {
                    const float h2v = leakyf_(acc[hf * 4 + i][j] + bv);
#pragma unroll
                    for (int jt = 0; jt < T_; ++jt)
                        part[i][jt] += h2v * Wt_s[jt][col];
                }
            }

            // 16-lane reduce: quad-DPP (VALU) + shfl_xor 4, 8
#pragma unroll
            for (int i = 0; i < 4; ++i)
#pragma unroll
                for (int jt = 0; jt < T_; ++jt) {
                    float v = part[i][jt];
                    v = dpp_add_<0xB1>(v);
                    v = dpp_add_<0x4E>(v);
                    v += __shfl_xor(v, 4, 16);
                    v += __shfl_xor(v, 8, 16);
                    part[i][jt] = v;
                }

            if (tx == 0) {
#pragma unroll
                for (int i = 0; i < 4; ++i) {
                    const int r = (hf == 0) ? (ty * 4 + i) : (64 + ty * 4 + i);
#pragma unroll
                    for (int jt = 0; jt < T_; ++jt)
                        lg_s[r][jt] += part[i][jt];
                }
            }
        }
    }

    __syncthreads();
    if (tid < XBM) {
        const int row = bm * XBM + tid;
#pragma unroll
        for (int jt = 0; jt < T_; ++jt)
            logits[(size_t)row * T_ + jt] = leakyf_(lg_s[tid][jt] + bt_s[jt]);
    }
}

// ---------------------------------------------------------------------------
// K3 (FALLBACK): fused MLP — round-3 measured version, used only if ws can't
// hold h1 (never expected given measured ws >= 249 MB).
// ---------------------------------------------------------------------------
#define BM 64
#define BN 128
#define BK 16
#define ASTR 68
#define BSTR 132
#define S1T 68   // h1T row stride

__global__ __launch_bounds__(256) void fused_mlp(
    const float* __restrict__ hcat,
    const float* __restrict__ W1, const float* __restrict__ b1,
    const float* __restrict__ W2, const float* __restrict__ b2,
    const float* __restrict__ Wt, const float* __restrict__ bt,
    float* __restrict__ logits)
{
    __shared__ float As[BK][ASTR];
    __shared__ float Bs[BK][BSTR];
    __shared__ float h1T[BN][S1T];
    __shared__ float Wt_s[T_][D_ + 2];
    __shared__ float b1_s[D_], b2_s[D_], bt_s[T_];

    const int tid  = threadIdx.x;
    const int row0 = blockIdx.x * BM;

    for (int i = tid; i < T_ * D_; i += 256) Wt_s[i >> 8][i & 255] = Wt[i];
    b1_s[tid] = b1[tid];
    b2_s[tid] = b2[tid];
    if (tid < T_) bt_s[tid] = bt[tid];

    const int tx = tid & 15;
    const int ty = tid >> 4;
    const int lrow = tid >> 2;
    const int lk   = (tid & 3) * 4;

    const float* arow = hcat + (size_t)(row0 + lrow) * D_ + lk;

    float acc2[2][4][8];
#pragma unroll
    for (int q = 0; q < 2; ++q)
#pragma unroll
        for (int i = 0; i < 4; ++i)
#pragma unroll
            for (int j = 0; j < 8; ++j) acc2[q][i][j] = 0.0f;

    for (int n0t = 0; n0t < 2; ++n0t) {
        const int n0 = n0t * BN;

        float acc1[4][8];
#pragma unroll
        for (int i = 0; i < 4; ++i)
#pragma unroll
            for (int j = 0; j < 8; ++j) acc1[i][j] = 0.0f;

        for (int k0 = 0; k0 < D_; k0 += BK) {
            {
                const float4 v = *(const float4*)(arow + k0);
                As[lk + 0][lrow] = v.x; As[lk + 1][lrow] = v.y;
                As[lk + 2][lrow] = v.z; As[lk + 3][lrow] = v.w;
            }
#pragma unroll
            for (int p = 0; p < 2; ++p) {
                const int n = p * 64 + lrow;
                const float4 v = *(const float4*)(W1 + (size_t)(n0 + n) * D_ + k0 + lk);
                Bs[lk + 0][n] = v.x; Bs[lk + 1][n] = v.y;
                Bs[lk + 2][n] = v.z; Bs[lk + 3][n] = v.w;
            }
            __syncthreads();
#pragma unroll
            for (int k = 0; k < BK; ++k) {
                float a[4], bb[8];
                *(float4*)a        = *(const float4*)&As[k][ty * 4];
                *(float4*)(bb)     = *(const float4*)&Bs[k][tx * 4];
                *(float4*)(bb + 4) = *(const float4*)&Bs[k][64 + tx * 4];
#pragma unroll
                for (int i = 0; i < 4; ++i)
#pragma unroll
                    for (int j = 0; j < 8; ++j) acc1[i][j] += a[i] * bb[j];
            }
            __syncthreads();
        }

#pragma unroll
        for (int j = 0; j < 8; ++j) {
            const int nl = (j < 4) ? (tx * 4 + j) : (64 + tx * 4 + j - 4);
            const float bv = b1_s[n0 + nl];
            float4 v;
            v.x = leakyf_(acc1[0][j] + bv);
            v.y = leakyf_(acc1[1][j] + bv);
            v.z = leakyf_(acc1[2][j] + bv);
            v.w = leakyf_(acc1[3][j] + bv);
            *(float4*)&h1T[nl][ty * 4] = v;
        }
        __syncthreads();

#pragma unroll
        for (int n2t = 0; n2t < 2; ++n2t) {
            for (int kc = 0; kc < BN; kc += BK) {
#pragma unroll
                for (int p = 0; p < 2; ++p) {
                    const int n = p * 64 + lrow;
                    const float4 v = *(const float4*)(W2 + (size_t)(n2t * BN + n) * D_ + n0 + kc + lk);
                    Bs[lk + 0][n] = v.x; Bs[lk + 1][n] = v.y;
                    Bs[lk + 2][n] = v.z; Bs[lk + 3][n] = v.w;
                }
                __syncthreads();
#pragma unroll
                for (int k = 0; k < BK; ++k) {
                    float a[4], bb[8];
                    *(float4*)a        = *(const float4*)&h1T[kc + k][ty * 4];
                    *(float4*)(bb)     = *(const float4*)&Bs[k][tx * 4];
                    *(float4*)(bb + 4) = *(const float4*)&Bs[k][64 + tx * 4];
#pragma unroll
                    for (int i = 0; i < 4; ++i)
#pragma unroll
                        for (int j = 0; j < 8; ++j) acc2[n2t][i][j] += a[i] * bb[j];
                }
                __syncthreads();
            }
        }
    }

    float part[4][T_];
#pragma unroll
    for (int i = 0; i < 4; ++i)
#pragma unroll
        for (int jt = 0; jt < T_; ++jt) part[i][jt] = 0.0f;

#pragma unroll
    for (int q = 0; q < 2; ++q)
#pragma unroll
        for (int j = 0; j < 8; ++j) {
            const int n = q * BN + ((j < 4) ? (tx * 4 + j) : (64 + tx * 4 + j - 4));
            const float bv = b2_s[n];
            float h2v[4];
#pragma unroll
            for (int i = 0; i < 4; ++i) h2v[i] = leakyf_(acc2[q][i][j] + bv);
#pragma unroll
            for (int jt = 0; jt < T_; ++jt) {
                const float wv = Wt_s[jt][n];
#pragma unroll
                for (int i = 0; i < 4; ++i) part[i][jt] += h2v[i] * wv;
            }
        }

#pragma unroll
    for (int m = 1; m <= 8; m <<= 1)
#pragma unroll
        for (int i = 0; i < 4; ++i)
#pragma unroll
            for (int jt = 0; jt < T_; ++jt)
                part[i][jt] += __shfl_xor(part[i][jt], m, 16);

    if (tx == 0) {
#pragma unroll
        for (int i = 0; i < 4; ++i) {
            const int m = row0 + ty * 4 + i;
#pragma unroll
            for (int jt = 0; jt < T_; ++jt)
                logits[(size_t)m * T_ + jt] = leakyf_(part[i][jt] + bt_s[jt]);
        }
    }
}

// ---------------------------------------------------------------------------
// K4: Viterbi per sample — unchanged.
// ---------------------------------------------------------------------------
__global__ __launch_bounds__(64) void viterbi_kernel(
    const float* __restrict__ logits, const float* __restrict__ trans,
    float* __restrict__ out)
{
    const int b = blockIdx.x;
    const int lane = threadIdx.x;

    __shared__ unsigned char bp[L_][8];
    __shared__ int path_s[L_];

    float tr[T_];
    if (lane < T_) {
#pragma unroll
        for (int i = 0; i < T_; ++i) tr[i] = trans[i * T_ + lane];
    }
    const float* lg = logits + (size_t)b * L_ * T_;
    float prev = (lane < T_) ? lg[lane] : -1e30f;

    for (int t = 1; t < L_; ++t) {
        float m = -1e30f; int arg = 0;
#pragma unroll
        for (int i = 0; i < T_; ++i) {
            const float v = __shfl(prev, i, 64) + tr[i];
            if (v > m) { m = v; arg = i; }
        }
        const float obs = (lane < T_) ? lg[t * T_ + lane] : 0.0f;
        prev = obs + m;
        if (lane < T_) bp[t][lane] = (unsigned char)arg;
    }
    __syncthreads();

    float best = __shfl(prev, 0, 64); int tag = 0;
#pragma unroll
    for (int jj = 1; jj < T_; ++jj) {
        const float v = __shfl(prev, jj, 64);
        if (v > best) { best = v; tag = jj; }
    }
    if (lane == 0) {
        out[b] = best;
        path_s[L_ - 1] = tag;
        for (int t = L_ - 1; t >= 1; --t) {
            tag = bp[t][tag];
            path_s[t - 1] = tag;
        }
    }
    __syncthreads();
    for (int i = lane; i < L_; i += 64)
        out[B_ + (size_t)b * L_ + i] = (float)path_s[i];
}

// ---------------------------------------------------------------------------
extern "C" void kernel_launch(void* const* d_in, const int* in_sizes, int n_in,
                              void* d_out, int out_size, void* d_ws, size_t ws_size,
                              hipStream_t stream)
{
    (void)in_sizes; (void)n_in; (void)out_size;

    const int*   sent  = (const int*)  d_in[0];
    const float* emb   = (const float*)d_in[2];
    const float* Wih_f = (const float*)d_in[3];
    const float* Whh_f = (const float*)d_in[4];
    const float* bih_f = (const float*)d_in[5];
    const float* bhh_f = (const float*)d_in[6];
    const float* Wih_b = (const float*)d_in[7];
    const float* Whh_b = (const float*)d_in[8];
    const float* bih_b = (const float*)d_in[9];
    const float* bhh_b = (const float*)d_in[10];
    const float* W1    = (const float*)d_in[11];
    const float* b1    = (const float*)d_in[12];
    const float* W2    = (const float*)d_in[13];
    const float* b2    = (const float*)d_in[14];
    const float* Wt    = (const float*)d_in[15];
    const float* bt    = (const float*)d_in[16];
    const float* trans = (const float*)d_in[17];

    float* ws = (float*)d_ws;
    const size_t HCAT_E = (size_t)B_ * L_ * D_;     // 26,214,400 floats
    const size_t LG_E   = (size_t)B_ * L_ * T_;     //    614,400
    const size_t ST_E   = (size_t)2 * B_ * 2 * H_;  //    262,144
    const size_t H1_E   = HCAT_E;                   // h1 is B*L*D too
    float* hcat   = ws;
    float* logits = ws + HCAT_E;
    float* state  = logits + LG_E;
    float* xgc    = state + ST_E;

    // Adaptive time-chunk so the xg staging buffer fits in ws_size.
    // (measured: ws in [249,312) MB -> 3 chunks; P-table path infeasible)
    const size_t base  = HCAT_E + LG_E + ST_E;      // ~108 MB
    const size_t per_t = (size_t)2 * B_ * G4H_;     // 524,288 floats per timestep
    const size_t ws_f  = ws_size / sizeof(float);
    long long avail = (long long)ws_f - (long long)base;
    int Tc = (avail > 0) ? (int)(avail / (long long)per_t) : 0;
    if (Tc < 1)  Tc = 1;
    if (Tc > L_) Tc = L_;

    float* out = (float*)d_out;

    for (int c0 = 0; c0 < L_; c0 += Tc) {
        const int tc = (L_ - c0 < Tc) ? (L_ - c0) : Tc;
        gemm_xg_chunk<<<dim3(8 * tc, 4), 256, 0, stream>>>(
            sent, emb, Wih_f, Wih_b, bih_f, bhh_f, bih_b, bhh_b, xgc, c0, tc);
        lstm_scan_chunk<<<256, 512, 0, stream>>>(
            xgc, Whh_f, Whh_b, state, hcat, c0, tc);
    }

    if (avail >= (long long)H1_E) {
        // h1 aliases xgc: the LSTM phase is done with xgc before mlp1 runs.
        float* h1 = xgc;
        mlp1_gemm<<<dim3((B_ * L_) / XBM, 2), 256, 0, stream>>>(hcat, W1, b1, h1);
        mlp2tag<<<(B_ * L_) / XBM, 256, 0, stream>>>(h1, W2, b2, Wt, bt, logits);
    } else {
        fused_mlp<<<(B_ * L_) / BM, 256, 0, stream>>>(
            hcat, W1, b1, W2, b2, Wt, bt, logits);
    }
    viterbi_kernel<<<B_, 64, 0, stream>>>(logits, trans, out);
}